// Round 14
// baseline (367.914 us; speedup 1.0000x reference)
//
#include <hip/hip_runtime.h>
#include <hip/hip_bf16.h>
#include <stdint.h>
#include <stddef.h>

typedef _Float16 f16;
typedef __attribute__((ext_vector_type(8))) _Float16 f16x8;
typedef __attribute__((ext_vector_type(4))) float f32x4;

#define EPI_NONE 0
#define EPI_SILU 1
#define EPI_RES  2
#define OUT_F16    0
#define OUT_F32    1
#define OUT_VT     3   // write C transposed into VT[b][d][token], token = row
#define OUT_ESTATS 4   // write E=exp(S-m_blk) f16 + per-col block max/sumexp
#define OUT_QKV    5   // bcol<1024 -> QKf write; bcol>=1024 -> VT write (Cp2)

__device__ __forceinline__ void gll16(const f16* g, char* l) {
    __builtin_amdgcn_global_load_lds(
        (const __attribute__((address_space(1))) void*)g,
        (__attribute__((address_space(3))) void*)l, 16, 0, 0);
}

// ---------------------------------------------------------------------------
// fp16 m97-structure GEMM: C = A @ B^T, f32 accumulate.
// 128xBN tile, BK=64, 4 waves (2x2), mfma_f32_16x16x32_f16.
// LDS XOR-swizzle on K-tiles => 0 bank conflicts (r3). Ls out-staging gets
// its own XOR (col16-group ^ (row>>2)&3): r13's staging had 2.1M conflicts
// (rows 4 apart = same banks); this spreads the 4 hi-groups over all 32.
// SWZ2D=1 (QK^T): 16x8 block rectangle per XCD => FETCH 139->54MB (r11/12).
// AEC=1 (PV): B-operand scaled on the fly by cScale; DECZ=1: z encodes
// (k-half, batch) for split-K PV (kh=z>>2, b=z&3) — partial O halves.
// ASUM=1 (final proj): A-operand = O0+O1 summed in regs (one-step prefetch).
// ---------------------------------------------------------------------------
template<int BN, int EPI, int OUT, int AEC, int SWZ2D, int DECZ, int ASUM>
__global__ __launch_bounds__(256)
void gemm_f16(const f16* __restrict__ A, const f16* __restrict__ Bm,
              void* __restrict__ Cp, f16* __restrict__ Cp2,
              const f16* __restrict__ Res,
              float* __restrict__ mp, float* __restrict__ zp,
              const float* __restrict__ cScale,
              int kseg, int lda, int ldb, int ldc, int ldr,
              unsigned long long sA, unsigned long long sB, unsigned long long sC)
{
    constexpr int NWF = BN / 32;
    constexpr int NCH = BN / 8;                  // f16x8 chunks per tile row
    constexpr int LCH = (BN == 128) ? 4 : 3;     // log2(NCH)
    const size_t OHALF = 8388608;                // 16384*512 elems per O half

    int zb = blockIdx.z, kh = 0;
    if constexpr (DECZ) { kh = zb >> 2; zb &= 3; }
    const size_t zC = (size_t)zb * sC + (size_t)kh * OHALF;

    unsigned bxs, bys;
    if constexpr (SWZ2D) {
        // 32x32 grid; XCD = lin&7. Region per XCD: 16 rows x 8 cols.
        unsigned lin = blockIdx.y * 32 + blockIdx.x;
        unsigned c = lin & 7, idx = lin >> 3;            // idx 0..127
        bys = (c >> 2) * 16 + (idx >> 3);
        bxs = (c & 3) * 8 + (idx & 7);
    } else {
        unsigned nwg = gridDim.x * gridDim.y;
        unsigned lin = blockIdx.y * gridDim.x + blockIdx.x;
        unsigned cpx = nwg >> 3;
        unsigned swz = (lin & 7) * cpx + (lin >> 3);
        bxs = swz % gridDim.x; bys = swz / gridDim.x;
    }

    const int t    = threadIdx.x;
    const int w    = t >> 6;
    const int lane = t & 63;
    const int wr   = w >> 1, wc = w & 1;
    const int lo   = lane & 15, hi = lane >> 4;
    const int brow = bys * 128;
    const int bcol = bxs * BN;

    const f16* Ag = A + (size_t)zb * sA + kh * 2048;
    const f16* Bg = Bm + (size_t)zb * sB + kh * 2048;
    if constexpr (OUT == OUT_QKV) Ag += (size_t)(bcol >> 9) * 512;

    // LDS: As 16KB | Bs BN*128B. After the final K-loop barrier the whole
    // buffer is reused: smst (f32 stats) and Ls (f16 128xBN out-tile).
    __shared__ __align__(16) char ldsbuf[16384 + BN * 128];
    f16* As = (f16*)ldsbuf;
    f16* Bs = (f16*)(ldsbuf + 16384);
    float* smst = (float*)ldsbuf;
    f16* Ls = (f16*)ldsbuf;
    // out-staging swizzle: 16-col group XOR'd with (row>>2)&3
    auto lsX = [](int r, int c) { return (c ^ (((r >> 2) & 3) << 4)); };

    f32x4 acc[4][NWF];
#pragma unroll
    for (int m = 0; m < 4; ++m)
#pragma unroll
        for (int n = 0; n < NWF; ++n)
            acc[m][n] = (f32x4){0.f, 0.f, 0.f, 0.f};

    const int r0 = t >> 3;                             // row in 32-row stripe
    const int cswz = ((t & 7) ^ ((t >> 3) & 7)) * 8;   // inverse-swizzled src
    const int rA7  = lo & 7;                           // read-side row parity

    const float* cb = nullptr;
    f16x8 bq[NWF];
    float4 cq0, cq1;
    if constexpr (AEC) {
        cb = cScale + ((size_t)zb * 32 + (brow >> 7)) * 4096 + kh * 2048;
#pragma unroll
        for (int i = 0; i < NWF; ++i)
            bq[i] = *(const f16x8*)(Bg + (size_t)(bcol + i * 32 + r0) * ldb + cswz);
        cq0 = *(const float4*)(cb + cswz);
        cq1 = *(const float4*)(cb + cswz + 4);
    }
    f16x8 aq0[4], aq1[4];
    if constexpr (ASUM) {
#pragma unroll
        for (int i = 0; i < 4; ++i) {
            size_t off = (size_t)(brow + i * 32 + r0) * lda + cswz;
            aq0[i] = *(const f16x8*)(Ag + off);
            aq1[i] = *(const f16x8*)(Ag + off + OHALF);
        }
    }

    for (int k0 = 0; k0 < kseg; k0 += 64) {
        if constexpr (ASUM) {
#pragma unroll
            for (int i = 0; i < 4; ++i) {
                f16x8 s = aq0[i] + aq1[i];
                *(f16x8*)((char*)As + i * 4096 + t * 16) = s;
            }
            if (k0 + 64 < kseg) {
#pragma unroll
                for (int i = 0; i < 4; ++i) {
                    size_t off = (size_t)(brow + i * 32 + r0) * lda + k0 + 64 + cswz;
                    aq0[i] = *(const f16x8*)(Ag + off);
                    aq1[i] = *(const f16x8*)(Ag + off + OHALF);
                }
            }
        } else {
#pragma unroll
            for (int i = 0; i < 4; ++i)
                gll16(Ag + (size_t)(brow + i * 32 + r0) * lda + (k0 + cswz),
                      (char*)As + i * 4096 + w * 1024);
        }
        if constexpr (AEC) {
            float cf[8] = {cq0.x, cq0.y, cq0.z, cq0.w, cq1.x, cq1.y, cq1.z, cq1.w};
#pragma unroll
            for (int i = 0; i < NWF; ++i) {
                f16x8 ev = bq[i], pv;
#pragma unroll
                for (int j = 0; j < 8; ++j) pv[j] = (f16)((float)ev[j] * cf[j]);
                *(f16x8*)((char*)Bs + i * 4096 + t * 16) = pv;
            }
            if (k0 + 64 < kseg) {
#pragma unroll
                for (int i = 0; i < NWF; ++i)
                    bq[i] = *(const f16x8*)(Bg + (size_t)(bcol + i * 32 + r0) * ldb
                                            + (k0 + 64 + cswz));
                cq0 = *(const float4*)(cb + k0 + 64 + cswz);
                cq1 = *(const float4*)(cb + k0 + 64 + cswz + 4);
            }
        } else {
#pragma unroll
            for (int i = 0; i < NWF; ++i)
                gll16(Bg + (size_t)(bcol + i * 32 + r0) * ldb + (k0 + cswz),
                      (char*)Bs + i * 4096 + w * 1024);
        }
        __syncthreads();

#pragma unroll
        for (int kk = 0; kk < 64; kk += 32) {
            f16x8 aH[4], bH[NWF];
#pragma unroll
            for (int m = 0; m < 4; ++m) {
                int idx = (wr * 64 + m * 16 + lo) * 64 +
                          ((((kk >> 3) + hi) ^ rA7) * 8);
                aH[m] = *(const f16x8*)&As[idx];
            }
#pragma unroll
            for (int n = 0; n < NWF; ++n) {
                int idx = (wc * (BN / 2) + n * 16 + lo) * 64 +
                          ((((kk >> 3) + hi) ^ rA7) * 8);
                bH[n] = *(const f16x8*)&Bs[idx];
            }
#pragma unroll
            for (int m = 0; m < 4; ++m)
#pragma unroll
                for (int n = 0; n < NWF; ++n)
                    acc[m][n] = __builtin_amdgcn_mfma_f32_16x16x32_f16(
                        aH[m], bH[n], acc[m][n], 0, 0, 0);
        }
        __syncthreads();
    }
    // NOTE: final __syncthreads() above makes As/Bs dead -> smst/Ls reuse ok.

    if constexpr (OUT == OUT_ESTATS) {
        const size_t zS = (size_t)zb * (32 * 4096);
        // ---- phase A: full 128-row block-column max (smst) ----
        float mb[NWF];
#pragma unroll
        for (int n = 0; n < NWF; ++n) {
            float ml = acc[0][n][0];
#pragma unroll
            for (int m = 0; m < 4; ++m)
#pragma unroll
                for (int j = 0; j < 4; ++j) ml = fmaxf(ml, acc[m][n][j]);
            ml = fmaxf(ml, __shfl_xor(ml, 16));
            ml = fmaxf(ml, __shfl_xor(ml, 32));
            if (hi == 0) smst[wr * 128 + wc * 64 + n * 16 + lo] = ml;
        }
        __syncthreads();
#pragma unroll
        for (int n = 0; n < NWF; ++n) {
            int c = wc * 64 + n * 16 + lo;
            mb[n] = fmaxf(smst[c], smst[128 + c]);
        }
        __syncthreads();                 // all smst reads done before Ls writes
        // ---- phase B: e -> Ls (f16, swizzled) + z partial ----
        float zsum[NWF];
#pragma unroll
        for (int n = 0; n < NWF; ++n) {
            zsum[n] = 0.f;
            int lcol = wc * 64 + n * 16 + lo;
#pragma unroll
            for (int m = 0; m < 4; ++m)
#pragma unroll
                for (int j = 0; j < 4; ++j) {
                    int lrow = wr * 64 + m * 16 + hi * 4 + j;
                    float e = __expf(acc[m][n][j] - mb[n]);
                    zsum[n] += e;
                    Ls[lrow * BN + lsX(lrow, lcol)] = (f16)e;
                }
        }
        __syncthreads();
        // ---- packed E stores: full-line f16x8 rows (swizzled reads) ----
        for (int i = t; i < 128 * NCH; i += 256) {
            int r2 = i >> LCH, cc = i & (NCH - 1);
            f16x8 vv = *(const f16x8*)&Ls[r2 * BN + lsX(r2, cc * 8)];
            *(f16x8*)&((f16*)Cp)[(size_t)(brow + r2) * ldc + bcol + cc * 8 + zC] = vv;
        }
        __syncthreads();                 // Ls reads done; smst reusable
        // ---- phase C: z reduce -> zp; mp from mb directly ----
#pragma unroll
        for (int n = 0; n < NWF; ++n) {
            float zl = zsum[n];
            zl += __shfl_xor(zl, 16);
            zl += __shfl_xor(zl, 32);
            if (hi == 0) smst[wr * 128 + wc * 64 + n * 16 + lo] = zl;
        }
        __syncthreads();
        size_t o = zS + (size_t)(brow >> 7) * 4096 + bcol;
        if (t < 128) zp[o + t] = smst[t] + smst[128 + t];
        if (wr == 0 && hi == 0) {
#pragma unroll
            for (int n = 0; n < NWF; ++n)
                mp[o + wc * 64 + n * 16 + lo] = mb[n];
        }
        return;
    }

    if constexpr (OUT == OUT_F16 || OUT == OUT_QKV) {
        bool packed = (OUT == OUT_F16) || (bcol < 1024);
        if (packed) {
            // ---- stage tile to LDS (swizzled), then full-line f16x8 stores ----
#pragma unroll
            for (int m = 0; m < 4; ++m)
#pragma unroll
                for (int n = 0; n < NWF; ++n)
#pragma unroll
                    for (int j = 0; j < 4; ++j) {
                        int lrow = wr * 64 + m * 16 + hi * 4 + j;
                        int lcol = wc * (BN / 2) + n * 16 + lo;
                        float v = acc[m][n][j];
                        if (EPI == EPI_SILU) v = v / (1.f + __expf(-v));
                        if (EPI == EPI_RES)
                            v += (float)Res[(size_t)(brow + lrow) * ldr + bcol + lcol];
                        Ls[lrow * BN + lsX(lrow, lcol)] = (f16)v;
                    }
            __syncthreads();
            for (int i = t; i < 128 * NCH; i += 256) {
                int r2 = i >> LCH, cc = i & (NCH - 1);
                f16x8 vv = *(const f16x8*)&Ls[r2 * BN + lsX(r2, cc * 8)];
                *(f16x8*)&((f16*)Cp)[(size_t)(brow + r2) * ldc + bcol + cc * 8 + zC] = vv;
            }
        } else {
            // v -> VT transposed (8B packed stores, already line-friendly)
#pragma unroll
            for (int m = 0; m < 4; ++m)
#pragma unroll
                for (int n = 0; n < NWF; ++n) {
                    int row0 = brow + wr * 64 + m * 16 + hi * 4;
                    int col  = bcol + wc * (BN / 2) + n * 16 + lo - 1024;
                    int bb = row0 >> 12, n0 = row0 & 4095;
                    unsigned short u[4];
#pragma unroll
                    for (int j = 0; j < 4; ++j) {
                        f16 vb = (f16)acc[m][n][j];
                        u[j] = *(unsigned short*)&vb;
                    }
                    ushort4 pack = {u[0], u[1], u[2], u[3]};
                    *(ushort4*)&Cp2[((size_t)(bb * 512 + col) << 12) + n0] = pack;
                }
        }
        return;
    }

    // ---- OUT_VT / OUT_F32 direct epilogues ----
#pragma unroll
    for (int m = 0; m < 4; ++m) {
#pragma unroll
        for (int n = 0; n < NWF; ++n) {
            if constexpr (OUT == OUT_VT) {
                int row0 = brow + wr * 64 + m * 16 + hi * 4;
                int col  = bcol + wc * (BN / 2) + n * 16 + lo;    // d index
                int bb = row0 >> 12, n0 = row0 & 4095;
                unsigned short u[4];
#pragma unroll
                for (int j = 0; j < 4; ++j) {
                    f16 vb = (f16)acc[m][n][j];
                    u[j] = *(unsigned short*)&vb;
                }
                ushort4 pack = {u[0], u[1], u[2], u[3]};
                *(ushort4*)&((f16*)Cp)[((size_t)(bb * 512 + col) << 12) + n0] = pack;
            } else {
#pragma unroll
                for (int j = 0; j < 4; ++j) {
                    int row = brow + wr * 64 + m * 16 + hi * 4 + j;
                    int col = bcol + wc * (BN / 2) + n * 16 + lo;
                    size_t idx = (size_t)row * ldc + col + zC;
                    float v = acc[m][n][j];
                    if (EPI == EPI_SILU) v = v / (1.f + __expf(-v));
                    if (EPI == EPI_RES)  v += (float)Res[(size_t)row * ldr + col];
                    ((float*)Cp)[idx] = v;     // f32: full-line as-is
                }
            }
        }
    }
}

// ---- cast x fp32 -> fp16, 8 elems/thread ----
__global__ void cast_x_kernel(const float* __restrict__ x, f16* __restrict__ xf)
{
    size_t i = ((size_t)blockIdx.x * 256 + threadIdx.x) * 8;
    float4 a = *(const float4*)(x + i);
    float4 b = *(const float4*)(x + i + 4);
    f16x8 o;
    o[0] = (f16)a.x; o[1] = (f16)a.y; o[2] = (f16)a.z; o[3] = (f16)a.w;
    o[4] = (f16)b.x; o[5] = (f16)b.y; o[6] = (f16)b.z; o[7] = (f16)b.w;
    *(f16x8*)(xf + i) = o;
}

// ---- transpose + cast all 10 weights to fp16 (z = weight idx) ----
struct WPack { const float* W[10]; f16* H[10]; };

__global__ void transw_all_kernel(WPack p)
{
    const float* W = p.W[blockIdx.z];
    f16* WT = p.H[blockIdx.z];
    __shared__ float tile[32][33];
    int bx = blockIdx.x * 32, by = blockIdx.y * 32;
    int tx = threadIdx.x, ty = threadIdx.y;      // (32, 8)
#pragma unroll
    for (int i = 0; i < 32; i += 8)
        tile[ty + i][tx] = W[(size_t)(by + ty + i) * 512 + bx + tx];
    __syncthreads();
#pragma unroll
    for (int i = 0; i < 32; i += 8)
        WT[(size_t)(bx + ty + i) * 512 + by + tx] = (f16)tile[tx][ty + i];
}

// ---- combine 32 row-block partials -> per-(z, block, col) PV scale c ----
__global__ void colstats_comb_kernel(const float* __restrict__ mp,
                                     const float* __restrict__ zp,
                                     float* __restrict__ cB)
{
    size_t base = (size_t)blockIdx.y * (32 * 4096);
    int col = blockIdx.x * 256 + threadIdx.x;
    float m = -1e30f;
#pragma unroll
    for (int i = 0; i < 32; ++i) m = fmaxf(m, mp[base + i * 4096 + col]);
    float z = 0.f;
#pragma unroll
    for (int i = 0; i < 32; ++i)
        z += zp[base + i * 4096 + col] * __expf(mp[base + i * 4096 + col] - m);
    float r = 1.f / z;
#pragma unroll
    for (int i = 0; i < 32; ++i)
        cB[base + i * 4096 + col] = __expf(mp[base + i * 4096 + col] - m) * r;
}

// ---------------------------------------------------------------------------
extern "C" void kernel_launch(void* const* d_in, const int* in_sizes, int n_in,
                              void* d_out, int out_size, void* d_ws, size_t ws_size,
                              hipStream_t stream)
{
    const int B = 4, N = 4096, D = 512;
    const size_t MALL = (size_t)B * N;          // 16384
    const size_t ND = MALL * D;                 // 8,388,608 elems (16 MiB f16)
    const size_t NN = (size_t)N * N;            // 16,777,216 elems (32 MiB f16)
    const size_t WW = (size_t)D * D;            // 262144
    const float* x = (const float*)d_in[0];
    const float* Wf[10];
    for (int i = 0; i < 10; ++i) Wf[i] = (const float*)d_in[1 + i];
    // Wf: 0 qW1, 1 qW2, 2 kW1, 3 kW2, 4 vW1, 5 vW2, 6 aWq, 7 aWk, 8 aWv, 9 Wout

    char* ws = (char*)d_ws;
    size_t off = 0;
    auto carve = [&](size_t bytes) -> char* {
        char* p = ws + off;
        off = (off + bytes + 255) & ~(size_t)255;
        return p;
    };

    // E region: 128 MiB (4 planes, stride NN). Before QK^T it hosts
    //   xf [0,16M) | t1 [16M,64M) | h [64M,112M)   (all dead at E-write time)
    const size_t PLANE = NN * 2;                 // 33,554,432 B
    f16* E_all = (f16*)carve(4 * PLANE);
    f16* QKf   = (f16*)carve(PLANE);             // [16384][1024] Q|K
    f16* VT    = (f16*)carve((size_t)B * D * N * 2);   // 16 MiB
    f16* O     = (f16*)carve(2 * ND * 2);              // 32 MiB: O0 | O1
    f16* wc1   = (f16*)carve(3 * WW * 2);        // [qW1|kW1|vW1]^T
    f16* wc2   = (f16*)carve(3 * WW * 2);        // [qW2|kW2|vW2]^T
    f16* wcA   = (f16*)carve(3 * WW * 2);        // [aWq|aWk|aWv]^T
    f16* wo    = (f16*)carve(WW * 2);            // Wout^T
    float* mp  = (float*)carve((size_t)B * 32 * 4096 * 4);
    float* zp  = (float*)carve((size_t)B * 32 * 4096 * 4);
    float* cB  = (float*)carve((size_t)B * 32 * 4096 * 4);
    // total ~219 MB, under proven 263 MB.

    f16* xf = E_all;                             // 16 MiB
    f16* t1 = E_all + ND;                        // [16384][1536], 48 MiB
    f16* h  = t1 + MALL * 1536;                  // [16384][1536], 48 MiB
    (void)in_sizes; (void)n_in; (void)out_size; (void)ws_size;

    // ---- input cast + weight transposes ----
    cast_x_kernel<<<dim3((unsigned)(ND / 2048)), 256, 0, stream>>>(x, xf);
    WPack wp;
    wp.W[0] = Wf[0]; wp.H[0] = wc1;            // qW1
    wp.W[1] = Wf[2]; wp.H[1] = wc1 + WW;       // kW1
    wp.W[2] = Wf[4]; wp.H[2] = wc1 + 2 * WW;   // vW1
    wp.W[3] = Wf[1]; wp.H[3] = wc2;            // qW2
    wp.W[4] = Wf[3]; wp.H[4] = wc2 + WW;       // kW2
    wp.W[5] = Wf[5]; wp.H[5] = wc2 + 2 * WW;   // vW2
    wp.W[6] = Wf[6]; wp.H[6] = wcA;            // aWq
    wp.W[7] = Wf[7]; wp.H[7] = wcA + WW;       // aWk
    wp.W[8] = Wf[8]; wp.H[8] = wcA + 2 * WW;   // aWv
    wp.W[9] = Wf[9]; wp.H[9] = wo;             // Wout
    transw_all_kernel<<<dim3(16, 16, 10), dim3(32, 8), 0, stream>>>(wp);

    // ---- fused ResiMLP stage 1: t1 = silu(x @ [qW1|kW1|vW1]) ----
    gemm_f16<128, EPI_SILU, OUT_F16, 0, 0, 0, 0><<<dim3(12, 128), 256, 0, stream>>>(
        xf, wc1, t1, nullptr, nullptr, nullptr, nullptr, nullptr,
        512, 512, 512, 1536, 512, 0, 0, 0);
    // ---- stage 2 (z=3): h_z = t1_z @ W2_z + xf (f16 residual) ----
    gemm_f16<128, EPI_RES, OUT_F16, 0, 0, 0, 0><<<dim3(4, 128, 3), 256, 0, stream>>>(
        t1, wc2, h, nullptr, xf, nullptr, nullptr, nullptr,
        512, 1536, 512, 1536, 512, 512, WW, 512);
    // ---- stage 3 merged q,k,v: QKf cols + VT transposed (one dispatch) ----
    gemm_f16<128, EPI_NONE, OUT_QKV, 0, 0, 0, 0><<<dim3(12, 128), 256, 0, stream>>>(
        h, wcA, QKf, VT, nullptr, nullptr, nullptr, nullptr,
        512, 1536, 512, 1024, 512, 0, 0, 0);

    // ---- QK^T z=4: E[b] = exp(Q_b K_b^T - m_blk) + per-block stats ----
    gemm_f16<128, EPI_NONE, OUT_ESTATS, 0, 1, 0, 0><<<dim3(32, 32, 4), 256, 0, stream>>>(
        QKf, QKf + 512, E_all, nullptr, nullptr, mp, zp, nullptr,
        512, 1024, 1024, 4096, 4096,
        (unsigned long long)N * 1024, (unsigned long long)N * 1024, NN);
    // ---- combine partials -> cB[b][blk][col] ----
    colstats_comb_kernel<<<dim3(16, 4), 256, 0, stream>>>(mp, zp, cB);

    // ---- split-K z-batched PV: O[kh][b] = E[b,kh] @ (c * VT[b,kh])^T ----
    gemm_f16<64, EPI_NONE, OUT_F16, 1, 0, 1, 0><<<dim3(8, 32, 8), 256, 0, stream>>>(
        E_all, VT, O, nullptr, nullptr, nullptr, nullptr, cB,
        2048, 4096, 4096, 512, 512,
        NN, (unsigned long long)D * N, (unsigned long long)N * D);

    // ---- final projection: d_out = (O0 + O1) @ Wout (f32 out, ASUM) ----
    gemm_f16<128, EPI_NONE, OUT_F32, 0, 0, 0, 1><<<dim3(4, 128), 256, 0, stream>>>(
        O, wo, d_out, nullptr, nullptr, nullptr, nullptr, nullptr,
        512, 512, 512, 512, 512, 0, 0, 0);
}

// Round 15
// 363.983 us; speedup vs baseline: 1.0108x; 1.0108x over previous
//
#include <hip/hip_runtime.h>
#include <hip/hip_bf16.h>
#include <stdint.h>
#include <stddef.h>

typedef _Float16 f16;
typedef __attribute__((ext_vector_type(8))) _Float16 f16x8;
typedef __attribute__((ext_vector_type(4))) float f32x4;

#define EPI_NONE 0
#define EPI_SILU 1
#define EPI_RES  2
#define OUT_F16    0
#define OUT_F32    1
#define OUT_VT     3   // write C transposed into VT[b][d][token], token = row
#define OUT_ESTATS 4   // write E=exp(S-m_blk) f16 + per-col block max/sumexp
#define OUT_QKV    5   // bcol<1024 -> QKf write; bcol>=1024 -> VT write (Cp2)

__device__ __forceinline__ void gll16(const f16* g, char* l) {
    __builtin_amdgcn_global_load_lds(
        (const __attribute__((address_space(1))) void*)g,
        (__attribute__((address_space(3))) void*)l, 16, 0, 0);
}

// ---------------------------------------------------------------------------
// fp16 m97-structure GEMM: C = A @ B^T, f32 accumulate.
// 128xBN tile, BK=64, 4 waves (2x2), mfma_f32_16x16x32_f16.
// LDS XOR-swizzle on K-tiles => 0 bank conflicts (r3). Ls out-staging XOR
// (col16-group ^ (row>>2)&3) => staging conflicts 2.1M -> 0 (r14).
// SWZ2D=1 (QK^T): 16x8 block rectangle per XCD => FETCH 139->54MB (r11/12).
// AEC=1 (PV): B-operand scaled on the fly by cScale[z][qblk][k], reg-staged
// with one-step prefetch. E store via LDS staging + packed f16x8 full-line
// stores (r13: ESTATS 129->113us). NT stores NOT used (r11: +122MB WRITE).
// Split-K PV and reg-summed A (r14) REVERTED: +12us net.
// ---------------------------------------------------------------------------
template<int BN, int EPI, int OUT, int AEC, int SWZ2D>
__global__ __launch_bounds__(256)
void gemm_f16(const f16* __restrict__ A, const f16* __restrict__ Bm,
              void* __restrict__ Cp, f16* __restrict__ Cp2,
              const f16* __restrict__ Res,
              float* __restrict__ mp, float* __restrict__ zp,
              const float* __restrict__ cScale,
              int kseg, int lda, int ldb, int ldc, int ldr,
              unsigned long long sA, unsigned long long sB, unsigned long long sC)
{
    constexpr int NWF = BN / 32;
    constexpr int NCH = BN / 8;                  // f16x8 chunks per tile row
    constexpr int LCH = (BN == 128) ? 4 : 3;     // log2(NCH)

    const size_t zC = (size_t)blockIdx.z * sC;

    unsigned bxs, bys;
    if constexpr (SWZ2D) {
        // 32x32 grid; XCD = lin&7. Region per XCD: 16 rows x 8 cols.
        unsigned lin = blockIdx.y * 32 + blockIdx.x;
        unsigned c = lin & 7, idx = lin >> 3;            // idx 0..127
        bys = (c >> 2) * 16 + (idx >> 3);
        bxs = (c & 3) * 8 + (idx & 7);
    } else {
        unsigned nwg = gridDim.x * gridDim.y;
        unsigned lin = blockIdx.y * gridDim.x + blockIdx.x;
        unsigned cpx = nwg >> 3;
        unsigned swz = (lin & 7) * cpx + (lin >> 3);
        bxs = swz % gridDim.x; bys = swz / gridDim.x;
    }

    const int t    = threadIdx.x;
    const int w    = t >> 6;
    const int lane = t & 63;
    const int wr   = w >> 1, wc = w & 1;
    const int lo   = lane & 15, hi = lane >> 4;
    const int brow = bys * 128;
    const int bcol = bxs * BN;

    const f16* Ag = A + (size_t)blockIdx.z * sA;
    const f16* Bg = Bm + (size_t)blockIdx.z * sB;
    if constexpr (OUT == OUT_QKV) Ag += (size_t)(bcol >> 9) * 512;

    // LDS: As 16KB | Bs BN*128B. After the final K-loop barrier the whole
    // buffer is reused: smst (f32 stats) and Ls (f16 128xBN out-tile).
    __shared__ __align__(16) char ldsbuf[16384 + BN * 128];
    f16* As = (f16*)ldsbuf;
    f16* Bs = (f16*)(ldsbuf + 16384);
    float* smst = (float*)ldsbuf;
    f16* Ls = (f16*)ldsbuf;
    // out-staging swizzle: 16-col group XOR'd with (row>>2)&3
    auto lsX = [](int r, int c) { return (c ^ (((r >> 2) & 3) << 4)); };

    f32x4 acc[4][NWF];
#pragma unroll
    for (int m = 0; m < 4; ++m)
#pragma unroll
        for (int n = 0; n < NWF; ++n)
            acc[m][n] = (f32x4){0.f, 0.f, 0.f, 0.f};

    const int r0 = t >> 3;                             // row in 32-row stripe
    const int cswz = ((t & 7) ^ ((t >> 3) & 7)) * 8;   // inverse-swizzled src
    const int rA7  = lo & 7;                           // read-side row parity

    const float* cb = nullptr;
    f16x8 bq[NWF];
    float4 cq0, cq1;
    if constexpr (AEC) {
        cb = cScale + ((size_t)blockIdx.z * 32 + (brow >> 7)) * 4096;
#pragma unroll
        for (int i = 0; i < NWF; ++i)
            bq[i] = *(const f16x8*)(Bg + (size_t)(bcol + i * 32 + r0) * ldb + cswz);
        cq0 = *(const float4*)(cb + cswz);
        cq1 = *(const float4*)(cb + cswz + 4);
    }

    for (int k0 = 0; k0 < kseg; k0 += 64) {
#pragma unroll
        for (int i = 0; i < 4; ++i)
            gll16(Ag + (size_t)(brow + i * 32 + r0) * lda + (k0 + cswz),
                  (char*)As + i * 4096 + w * 1024);
        if constexpr (AEC) {
            float cf[8] = {cq0.x, cq0.y, cq0.z, cq0.w, cq1.x, cq1.y, cq1.z, cq1.w};
#pragma unroll
            for (int i = 0; i < NWF; ++i) {
                f16x8 ev = bq[i], pv;
#pragma unroll
                for (int j = 0; j < 8; ++j) pv[j] = (f16)((float)ev[j] * cf[j]);
                *(f16x8*)((char*)Bs + i * 4096 + t * 16) = pv;
            }
            if (k0 + 64 < kseg) {
#pragma unroll
                for (int i = 0; i < NWF; ++i)
                    bq[i] = *(const f16x8*)(Bg + (size_t)(bcol + i * 32 + r0) * ldb
                                            + (k0 + 64 + cswz));
                cq0 = *(const float4*)(cb + k0 + 64 + cswz);
                cq1 = *(const float4*)(cb + k0 + 64 + cswz + 4);
            }
        } else {
#pragma unroll
            for (int i = 0; i < NWF; ++i)
                gll16(Bg + (size_t)(bcol + i * 32 + r0) * ldb + (k0 + cswz),
                      (char*)Bs + i * 4096 + w * 1024);
        }
        __syncthreads();

#pragma unroll
        for (int kk = 0; kk < 64; kk += 32) {
            f16x8 aH[4], bH[NWF];
#pragma unroll
            for (int m = 0; m < 4; ++m) {
                int idx = (wr * 64 + m * 16 + lo) * 64 +
                          ((((kk >> 3) + hi) ^ rA7) * 8);
                aH[m] = *(const f16x8*)&As[idx];
            }
#pragma unroll
            for (int n = 0; n < NWF; ++n) {
                int idx = (wc * (BN / 2) + n * 16 + lo) * 64 +
                          ((((kk >> 3) + hi) ^ rA7) * 8);
                bH[n] = *(const f16x8*)&Bs[idx];
            }
#pragma unroll
            for (int m = 0; m < 4; ++m)
#pragma unroll
                for (int n = 0; n < NWF; ++n)
                    acc[m][n] = __builtin_amdgcn_mfma_f32_16x16x32_f16(
                        aH[m], bH[n], acc[m][n], 0, 0, 0);
        }
        __syncthreads();
    }
    // NOTE: final __syncthreads() above makes As/Bs dead -> smst/Ls reuse ok.

    if constexpr (OUT == OUT_ESTATS) {
        const size_t zS = (size_t)blockIdx.z * (32 * 4096);
        // ---- phase A: full 128-row block-column max (smst) ----
        float mb[NWF];
#pragma unroll
        for (int n = 0; n < NWF; ++n) {
            float ml = acc[0][n][0];
#pragma unroll
            for (int m = 0; m < 4; ++m)
#pragma unroll
                for (int j = 0; j < 4; ++j) ml = fmaxf(ml, acc[m][n][j]);
            ml = fmaxf(ml, __shfl_xor(ml, 16));
            ml = fmaxf(ml, __shfl_xor(ml, 32));
            if (hi == 0) smst[wr * 128 + wc * 64 + n * 16 + lo] = ml;
        }
        __syncthreads();
#pragma unroll
        for (int n = 0; n < NWF; ++n) {
            int c = wc * 64 + n * 16 + lo;
            mb[n] = fmaxf(smst[c], smst[128 + c]);
        }
        __syncthreads();                 // all smst reads done before Ls writes
        // ---- phase B: e -> Ls (f16, swizzled) + z partial ----
        float zsum[NWF];
#pragma unroll
        for (int n = 0; n < NWF; ++n) {
            zsum[n] = 0.f;
            int lcol = wc * 64 + n * 16 + lo;
#pragma unroll
            for (int m = 0; m < 4; ++m)
#pragma unroll
                for (int j = 0; j < 4; ++j) {
                    int lrow = wr * 64 + m * 16 + hi * 4 + j;
                    float e = __expf(acc[m][n][j] - mb[n]);
                    zsum[n] += e;
                    Ls[lrow * BN + lsX(lrow, lcol)] = (f16)e;
                }
        }
        __syncthreads();
        // ---- packed E stores: full-line f16x8 rows (swizzled reads) ----
        for (int i = t; i < 128 * NCH; i += 256) {
            int r2 = i >> LCH, cc = i & (NCH - 1);
            f16x8 vv = *(const f16x8*)&Ls[r2 * BN + lsX(r2, cc * 8)];
            *(f16x8*)&((f16*)Cp)[(size_t)(brow + r2) * ldc + bcol + cc * 8 + zC] = vv;
        }
        __syncthreads();                 // Ls reads done; smst reusable
        // ---- phase C: z reduce -> zp; mp from mb directly ----
#pragma unroll
        for (int n = 0; n < NWF; ++n) {
            float zl = zsum[n];
            zl += __shfl_xor(zl, 16);
            zl += __shfl_xor(zl, 32);
            if (hi == 0) smst[wr * 128 + wc * 64 + n * 16 + lo] = zl;
        }
        __syncthreads();
        size_t o = zS + (size_t)(brow >> 7) * 4096 + bcol;
        if (t < 128) zp[o + t] = smst[t] + smst[128 + t];
        if (wr == 0 && hi == 0) {
#pragma unroll
            for (int n = 0; n < NWF; ++n)
                mp[o + wc * 64 + n * 16 + lo] = mb[n];
        }
        return;
    }

    if constexpr (OUT == OUT_F16 || OUT == OUT_QKV) {
        bool packed = (OUT == OUT_F16) || (bcol < 1024);
        if (packed) {
            // ---- stage tile to LDS (swizzled), then full-line f16x8 stores ----
#pragma unroll
            for (int m = 0; m < 4; ++m)
#pragma unroll
                for (int n = 0; n < NWF; ++n)
#pragma unroll
                    for (int j = 0; j < 4; ++j) {
                        int lrow = wr * 64 + m * 16 + hi * 4 + j;
                        int lcol = wc * (BN / 2) + n * 16 + lo;
                        float v = acc[m][n][j];
                        if (EPI == EPI_SILU) v = v / (1.f + __expf(-v));
                        if (EPI == EPI_RES)
                            v += (float)Res[(size_t)(brow + lrow) * ldr + bcol + lcol];
                        Ls[lrow * BN + lsX(lrow, lcol)] = (f16)v;
                    }
            __syncthreads();
            for (int i = t; i < 128 * NCH; i += 256) {
                int r2 = i >> LCH, cc = i & (NCH - 1);
                f16x8 vv = *(const f16x8*)&Ls[r2 * BN + lsX(r2, cc * 8)];
                *(f16x8*)&((f16*)Cp)[(size_t)(brow + r2) * ldc + bcol + cc * 8 + zC] = vv;
            }
        } else {
            // v -> VT transposed (8B packed stores, already line-friendly)
#pragma unroll
            for (int m = 0; m < 4; ++m)
#pragma unroll
                for (int n = 0; n < NWF; ++n) {
                    int row0 = brow + wr * 64 + m * 16 + hi * 4;
                    int col  = bcol + wc * (BN / 2) + n * 16 + lo - 1024;
                    int bb = row0 >> 12, n0 = row0 & 4095;
                    unsigned short u[4];
#pragma unroll
                    for (int j = 0; j < 4; ++j) {
                        f16 vb = (f16)acc[m][n][j];
                        u[j] = *(unsigned short*)&vb;
                    }
                    ushort4 pack = {u[0], u[1], u[2], u[3]};
                    *(ushort4*)&Cp2[((size_t)(bb * 512 + col) << 12) + n0] = pack;
                }
        }
        return;
    }

    // ---- OUT_VT / OUT_F32 direct epilogues ----
#pragma unroll
    for (int m = 0; m < 4; ++m) {
#pragma unroll
        for (int n = 0; n < NWF; ++n) {
            if constexpr (OUT == OUT_VT) {
                int row0 = brow + wr * 64 + m * 16 + hi * 4;
                int col  = bcol + wc * (BN / 2) + n * 16 + lo;    // d index
                int bb = row0 >> 12, n0 = row0 & 4095;
                unsigned short u[4];
#pragma unroll
                for (int j = 0; j < 4; ++j) {
                    f16 vb = (f16)acc[m][n][j];
                    u[j] = *(unsigned short*)&vb;
                }
                ushort4 pack = {u[0], u[1], u[2], u[3]};
                *(ushort4*)&((f16*)Cp)[((size_t)(bb * 512 + col) << 12) + n0] = pack;
            } else {
#pragma unroll
                for (int j = 0; j < 4; ++j) {
                    int row = brow + wr * 64 + m * 16 + hi * 4 + j;
                    int col = bcol + wc * (BN / 2) + n * 16 + lo;
                    size_t idx = (size_t)row * ldc + col + zC;
                    float v = acc[m][n][j];
                    if (EPI == EPI_SILU) v = v / (1.f + __expf(-v));
                    if (EPI == EPI_RES)  v += (float)Res[(size_t)row * ldr + col];
                    ((float*)Cp)[idx] = v;     // f32: full-line as-is
                }
            }
        }
    }
}

// ---- cast x fp32 -> fp16, 8 elems/thread ----
__global__ void cast_x_kernel(const float* __restrict__ x, f16* __restrict__ xf)
{
    size_t i = ((size_t)blockIdx.x * 256 + threadIdx.x) * 8;
    float4 a = *(const float4*)(x + i);
    float4 b = *(const float4*)(x + i + 4);
    f16x8 o;
    o[0] = (f16)a.x; o[1] = (f16)a.y; o[2] = (f16)a.z; o[3] = (f16)a.w;
    o[4] = (f16)b.x; o[5] = (f16)b.y; o[6] = (f16)b.z; o[7] = (f16)b.w;
    *(f16x8*)(xf + i) = o;
}

// ---- transpose + cast all 10 weights to fp16 (z = weight idx) ----
struct WPack { const float* W[10]; f16* H[10]; };

__global__ void transw_all_kernel(WPack p)
{
    const float* W = p.W[blockIdx.z];
    f16* WT = p.H[blockIdx.z];
    __shared__ float tile[32][33];
    int bx = blockIdx.x * 32, by = blockIdx.y * 32;
    int tx = threadIdx.x, ty = threadIdx.y;      // (32, 8)
#pragma unroll
    for (int i = 0; i < 32; i += 8)
        tile[ty + i][tx] = W[(size_t)(by + ty + i) * 512 + bx + tx];
    __syncthreads();
#pragma unroll
    for (int i = 0; i < 32; i += 8)
        WT[(size_t)(bx + ty + i) * 512 + by + tx] = (f16)tile[tx][ty + i];
}

// ---- combine 32 row-block partials -> per-(z, block, col) PV scale c ----
__global__ void colstats_comb_kernel(const float* __restrict__ mp,
                                     const float* __restrict__ zp,
                                     float* __restrict__ cB)
{
    size_t base = (size_t)blockIdx.y * (32 * 4096);
    int col = blockIdx.x * 256 + threadIdx.x;
    float m = -1e30f;
#pragma unroll
    for (int i = 0; i < 32; ++i) m = fmaxf(m, mp[base + i * 4096 + col]);
    float z = 0.f;
#pragma unroll
    for (int i = 0; i < 32; ++i)
        z += zp[base + i * 4096 + col] * __expf(mp[base + i * 4096 + col] - m);
    float r = 1.f / z;
#pragma unroll
    for (int i = 0; i < 32; ++i)
        cB[base + i * 4096 + col] = __expf(mp[base + i * 4096 + col] - m) * r;
}

// ---------------------------------------------------------------------------
extern "C" void kernel_launch(void* const* d_in, const int* in_sizes, int n_in,
                              void* d_out, int out_size, void* d_ws, size_t ws_size,
                              hipStream_t stream)
{
    const int B = 4, N = 4096, D = 512;
    const size_t MALL = (size_t)B * N;          // 16384
    const size_t ND = MALL * D;                 // 8,388,608 elems (16 MiB f16)
    const size_t NN = (size_t)N * N;            // 16,777,216 elems (32 MiB f16)
    const size_t WW = (size_t)D * D;            // 262144
    const float* x = (const float*)d_in[0];
    const float* Wf[10];
    for (int i = 0; i < 10; ++i) Wf[i] = (const float*)d_in[1 + i];
    // Wf: 0 qW1, 1 qW2, 2 kW1, 3 kW2, 4 vW1, 5 vW2, 6 aWq, 7 aWk, 8 aWv, 9 Wout

    char* ws = (char*)d_ws;
    size_t off = 0;
    auto carve = [&](size_t bytes) -> char* {
        char* p = ws + off;
        off = (off + bytes + 255) & ~(size_t)255;
        return p;
    };

    // E region: 128 MiB (4 planes, stride NN). Before QK^T it hosts
    //   xf [0,16M) | t1 [16M,64M) | h [64M,112M)   (all dead at E-write time)
    const size_t PLANE = NN * 2;                 // 33,554,432 B
    f16* E_all = (f16*)carve(4 * PLANE);
    f16* QKf   = (f16*)carve(PLANE);             // [16384][1024] Q|K
    f16* VT    = (f16*)carve((size_t)B * D * N * 2);   // 16 MiB
    f16* O     = (f16*)carve(ND * 2);                  // 16 MiB
    f16* wc1   = (f16*)carve(3 * WW * 2);        // [qW1|kW1|vW1]^T
    f16* wc2   = (f16*)carve(3 * WW * 2);        // [qW2|kW2|vW2]^T
    f16* wcA   = (f16*)carve(3 * WW * 2);        // [aWq|aWk|aWv]^T
    f16* wo    = (f16*)carve(WW * 2);            // Wout^T
    float* mp  = (float*)carve((size_t)B * 32 * 4096 * 4);
    float* zp  = (float*)carve((size_t)B * 32 * 4096 * 4);
    float* cB  = (float*)carve((size_t)B * 32 * 4096 * 4);
    // total ~203 MB, under proven 263 MB.

    f16* xf = E_all;                             // 16 MiB
    f16* t1 = E_all + ND;                        // [16384][1536], 48 MiB
    f16* h  = t1 + MALL * 1536;                  // [16384][1536], 48 MiB
    (void)in_sizes; (void)n_in; (void)out_size; (void)ws_size;

    // ---- input cast + weight transposes ----
    cast_x_kernel<<<dim3((unsigned)(ND / 2048)), 256, 0, stream>>>(x, xf);
    WPack wp;
    wp.W[0] = Wf[0]; wp.H[0] = wc1;            // qW1
    wp.W[1] = Wf[2]; wp.H[1] = wc1 + WW;       // kW1
    wp.W[2] = Wf[4]; wp.H[2] = wc1 + 2 * WW;   // vW1
    wp.W[3] = Wf[1]; wp.H[3] = wc2;            // qW2
    wp.W[4] = Wf[3]; wp.H[4] = wc2 + WW;       // kW2
    wp.W[5] = Wf[5]; wp.H[5] = wc2 + 2 * WW;   // vW2
    wp.W[6] = Wf[6]; wp.H[6] = wcA;            // aWq
    wp.W[7] = Wf[7]; wp.H[7] = wcA + WW;       // aWk
    wp.W[8] = Wf[8]; wp.H[8] = wcA + 2 * WW;   // aWv
    wp.W[9] = Wf[9]; wp.H[9] = wo;             // Wout
    transw_all_kernel<<<dim3(16, 16, 10), dim3(32, 8), 0, stream>>>(wp);

    // ---- fused ResiMLP stage 1: t1 = silu(x @ [qW1|kW1|vW1]) ----
    gemm_f16<128, EPI_SILU, OUT_F16, 0, 0><<<dim3(12, 128), 256, 0, stream>>>(
        xf, wc1, t1, nullptr, nullptr, nullptr, nullptr, nullptr,
        512, 512, 512, 1536, 512, 0, 0, 0);
    // ---- stage 2 (z=3): h_z = t1_z @ W2_z + xf (f16 residual) ----
    gemm_f16<128, EPI_RES, OUT_F16, 0, 0><<<dim3(4, 128, 3), 256, 0, stream>>>(
        t1, wc2, h, nullptr, xf, nullptr, nullptr, nullptr,
        512, 1536, 512, 1536, 512, 512, WW, 512);
    // ---- stage 3 merged q,k,v: QKf cols + VT transposed (one dispatch) ----
    gemm_f16<128, EPI_NONE, OUT_QKV, 0, 0><<<dim3(12, 128), 256, 0, stream>>>(
        h, wcA, QKf, VT, nullptr, nullptr, nullptr, nullptr,
        512, 1536, 512, 1024, 512, 0, 0, 0);

    // ---- QK^T z=4: E[b] = exp(Q_b K_b^T - m_blk) + per-block stats ----
    gemm_f16<128, EPI_NONE, OUT_ESTATS, 0, 1><<<dim3(32, 32, 4), 256, 0, stream>>>(
        QKf, QKf + 512, E_all, nullptr, nullptr, mp, zp, nullptr,
        512, 1024, 1024, 4096, 4096,
        (unsigned long long)N * 1024, (unsigned long long)N * 1024, NN);
    // ---- combine partials -> cB[b][blk][col] ----
    colstats_comb_kernel<<<dim3(16, 4), 256, 0, stream>>>(mp, zp, cB);

    // ---- z-batched PV: O[b] = E[b] @ (c[b] * VT[b])^T (B-side AEC) ----
    gemm_f16<64, EPI_NONE, OUT_F16, 1, 0><<<dim3(8, 32, 4), 256, 0, stream>>>(
        E_all, VT, O, nullptr, nullptr, nullptr, nullptr, cB,
        4096, 4096, 4096, 512, 512,
        NN, (unsigned long long)D * N, (unsigned long long)N * D);

    // ---- final projection: d_out = O @ Wout (f32 out) ----
    gemm_f16<128, EPI_NONE, OUT_F32, 0, 0><<<dim3(4, 128), 256, 0, stream>>>(
        O, wo, d_out, nullptr, nullptr, nullptr, nullptr, nullptr,
        512, 512, 512, 512, 512, 0, 0, 0);
}

// Round 16
// 352.313 us; speedup vs baseline: 1.0443x; 1.0331x over previous
//
#include <hip/hip_runtime.h>
#include <hip/hip_bf16.h>
#include <stdint.h>
#include <stddef.h>

typedef _Float16 f16;
typedef __attribute__((ext_vector_type(8))) _Float16 f16x8;
typedef __attribute__((ext_vector_type(4))) float f32x4;

#define EPI_NONE 0
#define EPI_SILU 1
#define EPI_RES  2
#define OUT_F16    0
#define OUT_F32    1
#define OUT_VT     3   // write C transposed into VT[b][d][token], token = row
#define OUT_ESTATS 4   // write E=exp(S-m_blk) f16 + per-col block max/sumexp
#define OUT_QKV    5   // bcol<1024 -> QKf write; bcol>=1024 -> VT write (Cp2)

__device__ __forceinline__ void gll16(const f16* g, char* l) {
    __builtin_amdgcn_global_load_lds(
        (const __attribute__((address_space(1))) void*)g,
        (__attribute__((address_space(3))) void*)l, 16, 0, 0);
}

// ---------------------------------------------------------------------------
// fp16 m97-structure GEMM: C = A @ B^T, f32 accumulate.
// 128xBN tile, BK=64, 4 waves (2x2), mfma_f32_16x16x32_f16.
// LDS XOR-swizzle on K-tiles => 0 bank conflicts (r3). Ls out-staging XOR
// (col16-group ^ (row>>2)&3) => staging conflicts 2.1M -> 0 (r14).
// SWZ2D=1 (QK^T): 16x8 block rectangle per XCD => FETCH 139->54MB (r11/12).
// AEC=1 (PV): B-operand scaled by cScale (f16, packed f16x8 vector multiply
// -- r16: replaces scalar f32 convert chain), reg-staged one-step prefetch.
// E store via LDS staging + packed f16x8 full-line stores (r13). NT stores
// NOT used (r11: +122MB WRITE). Split-K PV / reg-summed A reverted (r14).
// ---------------------------------------------------------------------------
template<int BN, int EPI, int OUT, int AEC, int SWZ2D>
__global__ __launch_bounds__(256)
void gemm_f16(const f16* __restrict__ A, const f16* __restrict__ Bm,
              void* __restrict__ Cp, f16* __restrict__ Cp2,
              const f16* __restrict__ Res,
              float* __restrict__ mp, float* __restrict__ zp,
              const f16* __restrict__ cScale,
              int kseg, int lda, int ldb, int ldc, int ldr,
              unsigned long long sA, unsigned long long sB, unsigned long long sC)
{
    constexpr int NWF = BN / 32;
    constexpr int NCH = BN / 8;                  // f16x8 chunks per tile row
    constexpr int LCH = (BN == 128) ? 4 : 3;     // log2(NCH)

    const size_t zC = (size_t)blockIdx.z * sC;

    unsigned bxs, bys;
    if constexpr (SWZ2D) {
        // 32x32 grid; XCD = lin&7. Region per XCD: 16 rows x 8 cols.
        unsigned lin = blockIdx.y * 32 + blockIdx.x;
        unsigned c = lin & 7, idx = lin >> 3;            // idx 0..127
        bys = (c >> 2) * 16 + (idx >> 3);
        bxs = (c & 3) * 8 + (idx & 7);
    } else {
        unsigned nwg = gridDim.x * gridDim.y;
        unsigned lin = blockIdx.y * gridDim.x + blockIdx.x;
        unsigned cpx = nwg >> 3;
        unsigned swz = (lin & 7) * cpx + (lin >> 3);
        bxs = swz % gridDim.x; bys = swz / gridDim.x;
    }

    const int t    = threadIdx.x;
    const int w    = t >> 6;
    const int lane = t & 63;
    const int wr   = w >> 1, wc = w & 1;
    const int lo   = lane & 15, hi = lane >> 4;
    const int brow = bys * 128;
    const int bcol = bxs * BN;

    const f16* Ag = A + (size_t)blockIdx.z * sA;
    const f16* Bg = Bm + (size_t)blockIdx.z * sB;
    if constexpr (OUT == OUT_QKV) Ag += (size_t)(bcol >> 9) * 512;

    // LDS: As 16KB | Bs BN*128B. After the final K-loop barrier the whole
    // buffer is reused: smst (f32 stats) and Ls (f16 128xBN out-tile).
    __shared__ __align__(16) char ldsbuf[16384 + BN * 128];
    f16* As = (f16*)ldsbuf;
    f16* Bs = (f16*)(ldsbuf + 16384);
    float* smst = (float*)ldsbuf;
    f16* Ls = (f16*)ldsbuf;
    // out-staging swizzle: 16-col group XOR'd with (row>>2)&3
    auto lsX = [](int r, int c) { return (c ^ (((r >> 2) & 3) << 4)); };

    f32x4 acc[4][NWF];
#pragma unroll
    for (int m = 0; m < 4; ++m)
#pragma unroll
        for (int n = 0; n < NWF; ++n)
            acc[m][n] = (f32x4){0.f, 0.f, 0.f, 0.f};

    const int r0 = t >> 3;                             // row in 32-row stripe
    const int cswz = ((t & 7) ^ ((t >> 3) & 7)) * 8;   // inverse-swizzled src
    const int rA7  = lo & 7;                           // read-side row parity

    const f16* cb = nullptr;
    f16x8 bq[NWF];
    f16x8 cq;
    if constexpr (AEC) {
        cb = cScale + ((size_t)blockIdx.z * 32 + (brow >> 7)) * 4096;
#pragma unroll
        for (int i = 0; i < NWF; ++i)
            bq[i] = *(const f16x8*)(Bg + (size_t)(bcol + i * 32 + r0) * ldb + cswz);
        cq = *(const f16x8*)(cb + cswz);
    }

    for (int k0 = 0; k0 < kseg; k0 += 64) {
#pragma unroll
        for (int i = 0; i < 4; ++i)
            gll16(Ag + (size_t)(brow + i * 32 + r0) * lda + (k0 + cswz),
                  (char*)As + i * 4096 + w * 1024);
        if constexpr (AEC) {
#pragma unroll
            for (int i = 0; i < NWF; ++i) {
                f16x8 pv = bq[i] * cq;           // packed f16 multiply (r16)
                *(f16x8*)((char*)Bs + i * 4096 + t * 16) = pv;
            }
            if (k0 + 64 < kseg) {
#pragma unroll
                for (int i = 0; i < NWF; ++i)
                    bq[i] = *(const f16x8*)(Bg + (size_t)(bcol + i * 32 + r0) * ldb
                                            + (k0 + 64 + cswz));
                cq = *(const f16x8*)(cb + k0 + 64 + cswz);
            }
        } else {
#pragma unroll
            for (int i = 0; i < NWF; ++i)
                gll16(Bg + (size_t)(bcol + i * 32 + r0) * ldb + (k0 + cswz),
                      (char*)Bs + i * 4096 + w * 1024);
        }
        __syncthreads();

#pragma unroll
        for (int kk = 0; kk < 64; kk += 32) {
            f16x8 aH[4], bH[NWF];
#pragma unroll
            for (int m = 0; m < 4; ++m) {
                int idx = (wr * 64 + m * 16 + lo) * 64 +
                          ((((kk >> 3) + hi) ^ rA7) * 8);
                aH[m] = *(const f16x8*)&As[idx];
            }
#pragma unroll
            for (int n = 0; n < NWF; ++n) {
                int idx = (wc * (BN / 2) + n * 16 + lo) * 64 +
                          ((((kk >> 3) + hi) ^ rA7) * 8);
                bH[n] = *(const f16x8*)&Bs[idx];
            }
#pragma unroll
            for (int m = 0; m < 4; ++m)
#pragma unroll
                for (int n = 0; n < NWF; ++n)
                    acc[m][n] = __builtin_amdgcn_mfma_f32_16x16x32_f16(
                        aH[m], bH[n], acc[m][n], 0, 0, 0);
        }
        __syncthreads();
    }
    // NOTE: final __syncthreads() above makes As/Bs dead -> smst/Ls reuse ok.

    if constexpr (OUT == OUT_ESTATS) {
        const size_t zS = (size_t)blockIdx.z * (32 * 4096);
        // ---- phase A: full 128-row block-column max (smst) ----
        float mb[NWF];
#pragma unroll
        for (int n = 0; n < NWF; ++n) {
            float ml = acc[0][n][0];
#pragma unroll
            for (int m = 0; m < 4; ++m)
#pragma unroll
                for (int j = 0; j < 4; ++j) ml = fmaxf(ml, acc[m][n][j]);
            ml = fmaxf(ml, __shfl_xor(ml, 16));
            ml = fmaxf(ml, __shfl_xor(ml, 32));
            if (hi == 0) smst[wr * 128 + wc * 64 + n * 16 + lo] = ml;
        }
        __syncthreads();
#pragma unroll
        for (int n = 0; n < NWF; ++n) {
            int c = wc * 64 + n * 16 + lo;
            mb[n] = fmaxf(smst[c], smst[128 + c]);
        }
        __syncthreads();                 // all smst reads done before Ls writes
        // ---- phase B: e -> Ls (f16, swizzled) + z partial ----
        float zsum[NWF];
#pragma unroll
        for (int n = 0; n < NWF; ++n) {
            zsum[n] = 0.f;
            int lcol = wc * 64 + n * 16 + lo;
#pragma unroll
            for (int m = 0; m < 4; ++m)
#pragma unroll
                for (int j = 0; j < 4; ++j) {
                    int lrow = wr * 64 + m * 16 + hi * 4 + j;
                    float e = __expf(acc[m][n][j] - mb[n]);
                    zsum[n] += e;
                    Ls[lrow * BN + lsX(lrow, lcol)] = (f16)e;
                }
        }
        __syncthreads();
        // ---- packed E stores: full-line f16x8 rows (swizzled reads) ----
        for (int i = t; i < 128 * NCH; i += 256) {
            int r2 = i >> LCH, cc = i & (NCH - 1);
            f16x8 vv = *(const f16x8*)&Ls[r2 * BN + lsX(r2, cc * 8)];
            *(f16x8*)&((f16*)Cp)[(size_t)(brow + r2) * ldc + bcol + cc * 8 + zC] = vv;
        }
        __syncthreads();                 // Ls reads done; smst reusable
        // ---- phase C: z reduce -> zp; mp from mb directly ----
#pragma unroll
        for (int n = 0; n < NWF; ++n) {
            float zl = zsum[n];
            zl += __shfl_xor(zl, 16);
            zl += __shfl_xor(zl, 32);
            if (hi == 0) smst[wr * 128 + wc * 64 + n * 16 + lo] = zl;
        }
        __syncthreads();
        size_t o = zS + (size_t)(brow >> 7) * 4096 + bcol;
        if (t < 128) zp[o + t] = smst[t] + smst[128 + t];
        if (wr == 0 && hi == 0) {
#pragma unroll
            for (int n = 0; n < NWF; ++n)
                mp[o + wc * 64 + n * 16 + lo] = mb[n];
        }
        return;
    }

    if constexpr (OUT == OUT_F16 || OUT == OUT_QKV) {
        bool packed = (OUT == OUT_F16) || (bcol < 1024);
        if (packed) {
            // ---- stage tile to LDS (swizzled), then full-line f16x8 stores ----
#pragma unroll
            for (int m = 0; m < 4; ++m)
#pragma unroll
                for (int n = 0; n < NWF; ++n)
#pragma unroll
                    for (int j = 0; j < 4; ++j) {
                        int lrow = wr * 64 + m * 16 + hi * 4 + j;
                        int lcol = wc * (BN / 2) + n * 16 + lo;
                        float v = acc[m][n][j];
                        if (EPI == EPI_SILU) v = v / (1.f + __expf(-v));
                        if (EPI == EPI_RES)
                            v += (float)Res[(size_t)(brow + lrow) * ldr + bcol + lcol];
                        Ls[lrow * BN + lsX(lrow, lcol)] = (f16)v;
                    }
            __syncthreads();
            for (int i = t; i < 128 * NCH; i += 256) {
                int r2 = i >> LCH, cc = i & (NCH - 1);
                f16x8 vv = *(const f16x8*)&Ls[r2 * BN + lsX(r2, cc * 8)];
                *(f16x8*)&((f16*)Cp)[(size_t)(brow + r2) * ldc + bcol + cc * 8 + zC] = vv;
            }
        } else {
            // v -> VT transposed (8B packed stores, already line-friendly)
#pragma unroll
            for (int m = 0; m < 4; ++m)
#pragma unroll
                for (int n = 0; n < NWF; ++n) {
                    int row0 = brow + wr * 64 + m * 16 + hi * 4;
                    int col  = bcol + wc * (BN / 2) + n * 16 + lo - 1024;
                    int bb = row0 >> 12, n0 = row0 & 4095;
                    unsigned short u[4];
#pragma unroll
                    for (int j = 0; j < 4; ++j) {
                        f16 vb = (f16)acc[m][n][j];
                        u[j] = *(unsigned short*)&vb;
                    }
                    ushort4 pack = {u[0], u[1], u[2], u[3]};
                    *(ushort4*)&Cp2[((size_t)(bb * 512 + col) << 12) + n0] = pack;
                }
        }
        return;
    }

    // ---- OUT_VT / OUT_F32 direct epilogues ----
#pragma unroll
    for (int m = 0; m < 4; ++m) {
#pragma unroll
        for (int n = 0; n < NWF; ++n) {
            if constexpr (OUT == OUT_VT) {
                int row0 = brow + wr * 64 + m * 16 + hi * 4;
                int col  = bcol + wc * (BN / 2) + n * 16 + lo;    // d index
                int bb = row0 >> 12, n0 = row0 & 4095;
                unsigned short u[4];
#pragma unroll
                for (int j = 0; j < 4; ++j) {
                    f16 vb = (f16)acc[m][n][j];
                    u[j] = *(unsigned short*)&vb;
                }
                ushort4 pack = {u[0], u[1], u[2], u[3]};
                *(ushort4*)&((f16*)Cp)[((size_t)(bb * 512 + col) << 12) + n0] = pack;
            } else {
#pragma unroll
                for (int j = 0; j < 4; ++j) {
                    int row = brow + wr * 64 + m * 16 + hi * 4 + j;
                    int col = bcol + wc * (BN / 2) + n * 16 + lo;
                    size_t idx = (size_t)row * ldc + col + zC;
                    float v = acc[m][n][j];
                    if (EPI == EPI_SILU) v = v / (1.f + __expf(-v));
                    if (EPI == EPI_RES)  v += (float)Res[(size_t)row * ldr + col];
                    ((float*)Cp)[idx] = v;     // f32: full-line as-is
                }
            }
        }
    }
}

// ---- merged prep: transpose+cast 10 weights (blocks 0..2559) and
//      cast x f32->f16 (blocks 2560..6655) in ONE dispatch (r16) ----
struct WPack { const float* W[10]; f16* H[10]; };

__global__ void prep_kernel(WPack p, const float* __restrict__ x,
                            f16* __restrict__ xf)
{
    int tx = threadIdx.x, ty = threadIdx.y;      // (32, 8)
    unsigned b = blockIdx.x;
    if (b < 2560) {
        // weight transpose: z = b/256, 16x16 tile grid within z
        unsigned wz = b >> 8, rem = b & 255;
        int bx = (rem & 15) * 32, by = (rem >> 4) * 32;
        const float* W = p.W[wz];
        f16* WT = p.H[wz];
        __shared__ float tile[32][33];
#pragma unroll
        for (int i = 0; i < 32; i += 8)
            tile[ty + i][tx] = W[(size_t)(by + ty + i) * 512 + bx + tx];
        __syncthreads();
#pragma unroll
        for (int i = 0; i < 32; i += 8)
            WT[(size_t)(bx + ty + i) * 512 + by + tx] = (f16)tile[tx][ty + i];
    } else {
        size_t i = (((size_t)(b - 2560)) * 256 + (ty * 32 + tx)) * 8;
        float4 a = *(const float4*)(x + i);
        float4 c = *(const float4*)(x + i + 4);
        f16x8 o;
        o[0] = (f16)a.x; o[1] = (f16)a.y; o[2] = (f16)a.z; o[3] = (f16)a.w;
        o[4] = (f16)c.x; o[5] = (f16)c.y; o[6] = (f16)c.z; o[7] = (f16)c.w;
        *(f16x8*)(xf + i) = o;
    }
}

// ---- combine 32 row-block partials -> per-(z, block, col) PV scale c (f16) ----
__global__ void colstats_comb_kernel(const float* __restrict__ mp,
                                     const float* __restrict__ zp,
                                     f16* __restrict__ cB)
{
    size_t base = (size_t)blockIdx.y * (32 * 4096);
    int col = blockIdx.x * 256 + threadIdx.x;
    float m = -1e30f;
#pragma unroll
    for (int i = 0; i < 32; ++i) m = fmaxf(m, mp[base + i * 4096 + col]);
    float z = 0.f;
#pragma unroll
    for (int i = 0; i < 32; ++i)
        z += zp[base + i * 4096 + col] * __expf(mp[base + i * 4096 + col] - m);
    float r = 1.f / z;
#pragma unroll
    for (int i = 0; i < 32; ++i)
        cB[base + i * 4096 + col] = (f16)(__expf(mp[base + i * 4096 + col] - m) * r);
}

// ---------------------------------------------------------------------------
extern "C" void kernel_launch(void* const* d_in, const int* in_sizes, int n_in,
                              void* d_out, int out_size, void* d_ws, size_t ws_size,
                              hipStream_t stream)
{
    const int B = 4, N = 4096, D = 512;
    const size_t MALL = (size_t)B * N;          // 16384
    const size_t ND = MALL * D;                 // 8,388,608 elems (16 MiB f16)
    const size_t NN = (size_t)N * N;            // 16,777,216 elems (32 MiB f16)
    const size_t WW = (size_t)D * D;            // 262144
    const float* x = (const float*)d_in[0];
    const float* Wf[10];
    for (int i = 0; i < 10; ++i) Wf[i] = (const float*)d_in[1 + i];
    // Wf: 0 qW1, 1 qW2, 2 kW1, 3 kW2, 4 vW1, 5 vW2, 6 aWq, 7 aWk, 8 aWv, 9 Wout

    char* ws = (char*)d_ws;
    size_t off = 0;
    auto carve = [&](size_t bytes) -> char* {
        char* p = ws + off;
        off = (off + bytes + 255) & ~(size_t)255;
        return p;
    };

    // E region: 128 MiB (4 planes, stride NN). Before QK^T it hosts
    //   xf [0,16M) | t1 [16M,64M) | h [64M,112M)   (all dead at E-write time)
    const size_t PLANE = NN * 2;                 // 33,554,432 B
    f16* E_all = (f16*)carve(4 * PLANE);
    f16* QKf   = (f16*)carve(PLANE);             // [16384][1024] Q|K
    f16* VT    = (f16*)carve((size_t)B * D * N * 2);   // 16 MiB
    f16* O     = (f16*)carve(ND * 2);                  // 16 MiB
    f16* wc1   = (f16*)carve(3 * WW * 2);        // [qW1|kW1|vW1]^T
    f16* wc2   = (f16*)carve(3 * WW * 2);        // [qW2|kW2|vW2]^T
    f16* wcA   = (f16*)carve(3 * WW * 2);        // [aWq|aWk|aWv]^T
    f16* wo    = (f16*)carve(WW * 2);            // Wout^T
    float* mp  = (float*)carve((size_t)B * 32 * 4096 * 4);
    float* zp  = (float*)carve((size_t)B * 32 * 4096 * 4);
    f16*   cB  = (f16*)carve((size_t)B * 32 * 4096 * 2);
    // total ~202 MB, under proven 263 MB.

    f16* xf = E_all;                             // 16 MiB
    f16* t1 = E_all + ND;                        // [16384][1536], 48 MiB
    f16* h  = t1 + MALL * 1536;                  // [16384][1536], 48 MiB
    (void)in_sizes; (void)n_in; (void)out_size; (void)ws_size;

    // ---- merged prep: weight transposes + x cast, one dispatch ----
    WPack wp;
    wp.W[0] = Wf[0]; wp.H[0] = wc1;            // qW1
    wp.W[1] = Wf[2]; wp.H[1] = wc1 + WW;       // kW1
    wp.W[2] = Wf[4]; wp.H[2] = wc1 + 2 * WW;   // vW1
    wp.W[3] = Wf[1]; wp.H[3] = wc2;            // qW2
    wp.W[4] = Wf[3]; wp.H[4] = wc2 + WW;       // kW2
    wp.W[5] = Wf[5]; wp.H[5] = wc2 + 2 * WW;   // vW2
    wp.W[6] = Wf[6]; wp.H[6] = wcA;            // aWq
    wp.W[7] = Wf[7]; wp.H[7] = wcA + WW;       // aWk
    wp.W[8] = Wf[8]; wp.H[8] = wcA + 2 * WW;   // aWv
    wp.W[9] = Wf[9]; wp.H[9] = wo;             // Wout
    prep_kernel<<<dim3(2560 + (unsigned)(ND / 2048)), dim3(32, 8), 0, stream>>>(
        wp, x, xf);

    // ---- fused ResiMLP stage 1: t1 = silu(x @ [qW1|kW1|vW1]) ----
    gemm_f16<128, EPI_SILU, OUT_F16, 0, 0><<<dim3(12, 128), 256, 0, stream>>>(
        xf, wc1, t1, nullptr, nullptr, nullptr, nullptr, nullptr,
        512, 512, 512, 1536, 512, 0, 0, 0);
    // ---- stage 2 (z=3): h_z = t1_z @ W2_z + xf (f16 residual) ----
    gemm_f16<128, EPI_RES, OUT_F16, 0, 0><<<dim3(4, 128, 3), 256, 0, stream>>>(
        t1, wc2, h, nullptr, xf, nullptr, nullptr, nullptr,
        512, 1536, 512, 1536, 512, 512, WW, 512);
    // ---- stage 3 merged q,k,v: QKf cols + VT transposed (one dispatch) ----
    gemm_f16<128, EPI_NONE, OUT_QKV, 0, 0><<<dim3(12, 128), 256, 0, stream>>>(
        h, wcA, QKf, VT, nullptr, nullptr, nullptr, nullptr,
        512, 1536, 512, 1024, 512, 0, 0, 0);

    // ---- QK^T z=4: E[b] = exp(Q_b K_b^T - m_blk) + per-block stats ----
    gemm_f16<128, EPI_NONE, OUT_ESTATS, 0, 1><<<dim3(32, 32, 4), 256, 0, stream>>>(
        QKf, QKf + 512, E_all, nullptr, nullptr, mp, zp, nullptr,
        512, 1024, 1024, 4096, 4096,
        (unsigned long long)N * 1024, (unsigned long long)N * 1024, NN);
    // ---- combine partials -> cB[b][blk][col] (f16) ----
    colstats_comb_kernel<<<dim3(16, 4), 256, 0, stream>>>(mp, zp, cB);

    // ---- z-batched PV: O[b] = E[b] @ (c[b] * VT[b])^T (packed-f16 AEC) ----
    gemm_f16<64, EPI_NONE, OUT_F16, 1, 0><<<dim3(8, 32, 4), 256, 0, stream>>>(
        E_all, VT, O, nullptr, nullptr, nullptr, nullptr, cB,
        4096, 4096, 4096, 512, 512,
        NN, (unsigned long long)D * N, (unsigned long long)N * D);

    // ---- final projection: d_out = O @ Wout (f32 out) ----
    gemm_f16<128, EPI_NONE, OUT_F32, 0, 0><<<dim3(4, 128), 256, 0, stream>>>(
        O, wo, d_out, nullptr, nullptr, nullptr, nullptr, nullptr,
        512, 512, 512, 512, 512, 0, 0, 0);
}